// Round 2
// baseline (249.526 us; speedup 1.0000x reference)
//
#include <hip/hip_runtime.h>
#include <math.h>

#define NDIM 128
#define NHID 512
#define NEXPERT 64
#define NTOK 1024

__device__ __forceinline__ float gelu_f(float v) {
    return 0.5f * v * (1.0f + erff(v * 0.7071067811865476f));
}

// K1: h1 = gelu(x @ gw1 + gb1)   x[1024,128] gw1[128,512] -> h1[1024,512]
__global__ __launch_bounds__(256) void gate1_kernel(
        const float* __restrict__ x, const float* __restrict__ gw1,
        const float* __restrict__ gb1, float* __restrict__ h1) {
    __shared__ float xs[8 * NDIM];
    const int j = threadIdx.x;
    const int t0 = blockIdx.x * 8;
    for (int i = j; i < 8 * NDIM; i += 256) xs[i] = x[t0 * NDIM + i];
    __syncthreads();
    float acc0[8], acc1[8];
#pragma unroll
    for (int t = 0; t < 8; ++t) { acc0[t] = 0.f; acc1[t] = 0.f; }
    for (int k = 0; k < NDIM; ++k) {
        float w0 = gw1[k * NHID + j];
        float w1 = gw1[k * NHID + j + 256];
#pragma unroll
        for (int t = 0; t < 8; ++t) {
            float xv = xs[t * NDIM + k];
            acc0[t] += xv * w0;
            acc1[t] += xv * w1;
        }
    }
    const float b0 = gb1[j], b1 = gb1[j + 256];
#pragma unroll
    for (int t = 0; t < 8; ++t) {
        h1[(t0 + t) * NHID + j]       = gelu_f(acc0[t] + b0);
        h1[(t0 + t) * NHID + j + 256] = gelu_f(acc1[t] + b1);
    }
}

// K2: h2 = gelu(h1 @ gw2 + gb2)  h1[1024,512] gw2[512,512] -> h2[1024,512]
__global__ __launch_bounds__(256) void gate2_kernel(
        const float* __restrict__ h1, const float* __restrict__ gw2,
        const float* __restrict__ gb2, float* __restrict__ h2) {
    __shared__ float hs[8 * NHID];
    const int j = threadIdx.x;
    const int t0 = blockIdx.x * 8;
    const int f = blockIdx.y * 256 + j;
    for (int i = j; i < 8 * NHID; i += 256) hs[i] = h1[t0 * NHID + i];
    __syncthreads();
    float acc[8];
#pragma unroll
    for (int t = 0; t < 8; ++t) acc[t] = 0.f;
    for (int k = 0; k < NHID; ++k) {
        float w = gw2[k * NHID + f];
#pragma unroll
        for (int t = 0; t < 8; ++t) acc[t] += hs[t * NHID + k] * w;
    }
    const float b = gb2[f];
#pragma unroll
    for (int t = 0; t < 8; ++t) h2[(t0 + t) * NHID + f] = gelu_f(acc[t] + b);
}

// K3: scores = sigmoid(h2 @ gw3 + gb3); top-2 (jax tie-break: lower index);
// normalized weights. One wave per 4 tokens, lane = expert.
__global__ __launch_bounds__(256) void gate3_top2_kernel(
        const float* __restrict__ h2, const float* __restrict__ gw3,
        const float* __restrict__ gb3, int* __restrict__ eidx,
        float* __restrict__ wval) {
    __shared__ float hs[16 * NHID];
    const int j = threadIdx.x;
    const int t0 = blockIdx.x * 16;
    for (int i = j; i < 16 * NHID; i += 256) hs[i] = h2[t0 * NHID + i];
    __syncthreads();
    const int w = j >> 6;     // wave 0..3
    const int lane = j & 63;  // expert index
    float acc[4] = {0.f, 0.f, 0.f, 0.f};
    for (int k = 0; k < NHID; ++k) {
        float g = gw3[k * NEXPERT + lane];
#pragma unroll
        for (int i = 0; i < 4; ++i) acc[i] += hs[(w * 4 + i) * NHID + k] * g;
    }
    const float bias = gb3[lane];
#pragma unroll
    for (int i = 0; i < 4; ++i) {
        const int t = t0 + w * 4 + i;
        float s = 1.f / (1.f + expf(-(acc[i] + bias)));
        // argmax #1 (ties -> lowest index)
        float v = s; int ix = lane;
#pragma unroll
        for (int off = 32; off >= 1; off >>= 1) {
            float ov = __shfl_xor(v, off);
            int oi = __shfl_xor(ix, off);
            if (ov > v || (ov == v && oi < ix)) { v = ov; ix = oi; }
        }
        const float v0 = v; const int i0 = ix;
        // argmax #2 excluding i0 (sigmoid > 0, so -1 acts as -inf)
        float v2 = (lane == i0) ? -1.f : s; int ix2 = lane;
#pragma unroll
        for (int off = 32; off >= 1; off >>= 1) {
            float ov = __shfl_xor(v2, off);
            int oi = __shfl_xor(ix2, off);
            if (ov > v2 || (ov == v2 && oi < ix2)) { v2 = ov; ix2 = oi; }
        }
        if (lane == 0) {
            float inv = 1.f / (v0 + v2);
            eidx[t * 2] = i0;  eidx[t * 2 + 1] = ix2;
            wval[t * 2] = v0 * inv;  wval[t * 2 + 1] = v2 * inv;
        }
    }
}

// K3b: deterministic per-expert assignment lists. One block per expert.
// Thread j counts matches in its contiguous slice [j*8, j*8+8); an inclusive
// Hillis-Steele block scan gives deterministic write offsets (index order).
__global__ __launch_bounds__(256) void build_lists_kernel(
        const int* __restrict__ eidx, int* __restrict__ elist,
        int* __restrict__ ecnt) {
    const int e = blockIdx.x;
    const int j = threadIdx.x;
    __shared__ int cnts[256];
    int my[8];
    int mc = 0;
#pragma unroll
    for (int q = 0; q < 8; ++q) {
        int i = j * 8 + q;
        if (eidx[i] == e) my[mc++] = i;
    }
    cnts[j] = mc;
    __syncthreads();
    for (int off = 1; off < 256; off <<= 1) {
        int other = (j >= off) ? cnts[j - off] : 0;
        __syncthreads();
        cnts[j] += other;
        __syncthreads();
    }
    const int base = cnts[j] - mc;  // exclusive prefix
    for (int q = 0; q < mc; ++q) elist[e * (NTOK * 2) + base + q] = my[q];
    if (j == 255) ecnt[e] = cnts[255];
}

// K4: grouped expert FFN. grid (64 experts, MSPLIT). All m-blocks of one
// expert read the SAME deterministic list, so the b%MSPLIT partition is exact.
#define MSPLIT 4
__global__ __launch_bounds__(256) void expert_kernel(
        const float* __restrict__ x, const float* __restrict__ W1,
        const float* __restrict__ B1, const float* __restrict__ W2,
        const float* __restrict__ B2, const int* __restrict__ elist,
        const int* __restrict__ ecnt, float* __restrict__ ybuf) {
    const int e = blockIdx.x;
    const int m = blockIdx.y;
    __shared__ int ts[8];
    __shared__ float xs[8 * NDIM];
    __shared__ float tls[8 * NHID];
    const int j = threadIdx.x;
    const int n = ecnt[e];
    const int* le = elist + e * (NTOK * 2);
    const float* W1e = W1 + (size_t)e * NHID * NDIM;
    const float* W2e = W2 + (size_t)e * NDIM * NHID;
    for (int b = m; b * 8 < n; b += MSPLIT) {
        const int nb = min(8, n - b * 8);
        if (j < 8) ts[j] = (j < nb) ? le[b * 8 + j] : le[b * 8];
        __syncthreads();
        for (int i = j; i < nb * NDIM; i += 256) {
            int tt = i >> 7;
            xs[i] = x[(ts[tt] >> 1) * NDIM + (i & (NDIM - 1))];
        }
        __syncthreads();
        // layer1: f = p*64 + (j>>2), 4 threads share a row's K
        {
            const int g = j & 3, fg = j >> 2;
            for (int p = 0; p < 8; ++p) {
                const int f = p * 64 + fg;
                const float* wr = W1e + f * NDIM;
                float acc[8];
#pragma unroll
                for (int t = 0; t < 8; ++t) acc[t] = 0.f;
#pragma unroll
                for (int i2 = 0; i2 < 8; ++i2) {
                    const int kin = i2 * 16 + g * 4;
                    float4 wv = *(const float4*)(wr + kin);
#pragma unroll
                    for (int t = 0; t < 8; ++t) {
                        acc[t] += wv.x * xs[t * NDIM + kin]
                                + wv.y * xs[t * NDIM + kin + 1]
                                + wv.z * xs[t * NDIM + kin + 2]
                                + wv.w * xs[t * NDIM + kin + 3];
                    }
                }
#pragma unroll
                for (int t = 0; t < 8; ++t) {
                    acc[t] += __shfl_xor(acc[t], 1);
                    acc[t] += __shfl_xor(acc[t], 2);
                }
                if (g == 0) {
                    float bb = B1[e * NHID + f];
#pragma unroll
                    for (int t = 0; t < 8; ++t)
                        if (t < nb) tls[t * NHID + f] = gelu_f(acc[t] + bb);
                }
            }
        }
        __syncthreads();
        // layer2: d = j>>1, 2 threads share a row's K
        {
            const int g2 = j & 1, d = j >> 1;
            const float* wr2 = W2e + d * NHID;
            float acc[8];
#pragma unroll
            for (int t = 0; t < 8; ++t) acc[t] = 0.f;
#pragma unroll
            for (int i2 = 0; i2 < 64; ++i2) {
                const int kin = i2 * 8 + g2 * 4;
                float4 wv = *(const float4*)(wr2 + kin);
#pragma unroll
                for (int t = 0; t < 8; ++t) {
                    acc[t] += wv.x * tls[t * NHID + kin]
                            + wv.y * tls[t * NHID + kin + 1]
                            + wv.z * tls[t * NHID + kin + 2]
                            + wv.w * tls[t * NHID + kin + 3];
                }
            }
#pragma unroll
            for (int t = 0; t < 8; ++t) acc[t] += __shfl_xor(acc[t], 1);
            if (g2 == 0) {
                float bb = B2[e * NDIM + d];
                for (int t = 0; t < nb; ++t)
                    ybuf[ts[t] * NDIM + d] = gelu_f(acc[t] + bb);
            }
        }
        __syncthreads();
    }
}

// K5: out[t,d] = w0*y[t,0,d] + w1*y[t,1,d]
__global__ __launch_bounds__(256) void combine_kernel(
        const float* __restrict__ ybuf, const float* __restrict__ wval,
        float* __restrict__ out) {
    const int i = blockIdx.x * 256 + threadIdx.x;
    const int t = i >> 7, d = i & (NDIM - 1);
    out[i] = wval[t * 2] * ybuf[t * 2 * NDIM + d]
           + wval[t * 2 + 1] * ybuf[(t * 2 + 1) * NDIM + d];
}

extern "C" void kernel_launch(void* const* d_in, const int* in_sizes, int n_in,
                              void* d_out, int out_size, void* d_ws, size_t ws_size,
                              hipStream_t stream) {
    const float* x   = (const float*)d_in[0];
    const float* gw1 = (const float*)d_in[1];
    const float* gb1 = (const float*)d_in[2];
    const float* gw2 = (const float*)d_in[3];
    const float* gb2 = (const float*)d_in[4];
    const float* gw3 = (const float*)d_in[5];
    const float* gb3 = (const float*)d_in[6];
    const float* W1  = (const float*)d_in[7];
    const float* B1  = (const float*)d_in[8];
    const float* W2  = (const float*)d_in[9];
    const float* B2  = (const float*)d_in[10];
    float* out = (float*)d_out;

    char* ws = (char*)d_ws;
    float* h1    = (float*)(ws);                        // 2 MB
    float* h2    = (float*)(ws + (2u << 20));           // 2 MB
    float* ybuf  = (float*)(ws + (4u << 20));           // 1 MB
    int*   eidx  = (int*)  (ws + (5u << 20));           // 8 KB
    float* wval  = (float*)(ws + (5u << 20) + 8192);    // 8 KB
    int*   elist = (int*)  (ws + (5u << 20) + 16384);   // 512 KB
    int*   ecnt  = (int*)  (ws + (5u << 20) + 16384 + (NEXPERT * NTOK * 2 * 4));

    gate1_kernel<<<dim3(NTOK / 8), 256, 0, stream>>>(x, gw1, gb1, h1);
    gate2_kernel<<<dim3(NTOK / 8, 2), 256, 0, stream>>>(h1, gw2, gb2, h2);
    gate3_top2_kernel<<<dim3(NTOK / 16), 256, 0, stream>>>(h2, gw3, gb3, eidx, wval);
    build_lists_kernel<<<dim3(NEXPERT), 256, 0, stream>>>(eidx, elist, ecnt);
    expert_kernel<<<dim3(NEXPERT, MSPLIT), 256, 0, stream>>>(x, W1, B1, W2, B2, elist, ecnt, ybuf);
    combine_kernel<<<dim3(NTOK * NDIM / 256), 256, 0, stream>>>(ybuf, wval, out);
}